// Round 8
// baseline (211.856 us; speedup 1.0000x reference)
//
#include <hip/hip_runtime.h>

typedef unsigned short u16;
typedef unsigned char u8;
typedef __attribute__((ext_vector_type(8))) short s8v;
typedef __attribute__((ext_vector_type(4))) float f4v;
typedef __attribute__((ext_vector_type(2))) long l2v;

enum { MODE_SCALE = 2, MODE_FINAL = 3 };

__device__ __forceinline__ u16 f2bf(float f) {
  unsigned u = __builtin_bit_cast(unsigned, f);
  u += 0x7fffu + ((u >> 16) & 1u);
  return (u16)(u >> 16);
}
__device__ __forceinline__ float bf2f(u16 h) {
  unsigned u = ((unsigned)h) << 16;
  return __builtin_bit_cast(float, u);
}
__device__ __forceinline__ void gload16(const void* g, void* l) {
  __builtin_amdgcn_global_load_lds(
      (const __attribute__((address_space(1))) unsigned int*)g,
      (__attribute__((address_space(3))) unsigned int*)l, 16, 0, 0);
}
__device__ __forceinline__ unsigned pk4fp8(float a, float b, float c, float d) {
  int lo = __builtin_amdgcn_cvt_pk_fp8_f32(a, b, 0, false);
  return (unsigned)__builtin_amdgcn_cvt_pk_fp8_f32(c, d, lo, true);
}
__device__ __forceinline__ u8 f2fp8(float a) {
  return (u8)(__builtin_amdgcn_cvt_pk_fp8_f32(a, a, 0, false) & 0xff);
}
// k-interleave permutation within each aligned 64B k-group: byte j ->
// ((j>>3)&3)*16 + ((j>>5)&1)*8 + (j&7).  Chunk q (16B) of a row then holds
// [k 8q..8q+7][k 32+8q..32+8q+7] = both MFMA k-slices for lane quad q.
__device__ __forceinline__ int kperm(int j) {
  return (j & ~63) | (((j >> 3) & 3) << 4) | (((j >> 5) & 1) << 3) | (j & 7);
}

// ------- prep fat kernel: gn partial stats + weight->bf16 + zeroing -------
// blocks [0,512):    gn_stats (x partial sums, 2 channels/block)
// blocks [512,1536): w2bf (4 weight matrices -> bf16)
// blocks [1536,1540): zero rowsum (2x4096 f32)
__global__ __launch_bounds__(256) void prep(
    const float* __restrict__ x, const float* __restrict__ w0,
    const float* __restrict__ w1, const float* __restrict__ w2,
    const float* __restrict__ w3, float2* __restrict__ part,
    u16* __restrict__ wout, float* __restrict__ rowsum) {
  const int bid = blockIdx.x;
  const int t = threadIdx.x;
  if (bid < 512) {
    const float4* p4 = (const float4*)(x + (long)bid * 8192);
    float s = 0.f, q = 0.f;
#pragma unroll
    for (int j = 0; j < 8; ++j) {
      float4 f = p4[t + 256 * j];
      s += f.x + f.y + f.z + f.w;
      q += f.x * f.x + f.y * f.y + f.z * f.z + f.w * f.w;
    }
#pragma unroll
    for (int o = 32; o; o >>= 1) {
      s += __shfl_xor(s, o, 64);
      q += __shfl_xor(q, o, 64);
    }
    __shared__ float rs[4], rq[4];
    int lane = t & 63, wv = t >> 6;
    if (lane == 0) { rs[wv] = s; rq[wv] = q; }
    __syncthreads();
    if (t == 0)
      part[bid] = make_float2(rs[0] + rs[1] + rs[2] + rs[3],
                              rq[0] + rq[1] + rq[2] + rq[3]);
  } else if (bid < 1536) {
    int wb = bid - 512;
    int which = wb >> 8;
    const float* w = which == 0 ? w0 : which == 1 ? w1 : which == 2 ? w2 : w3;
    int i = ((wb & 255) * 256 + t) * 4;
    float4 f = *(const float4*)(w + i);
    u16* o = wout + (long)which * 262144 + i;
    ushort4 r;
    r.x = f2bf(f.x); r.y = f2bf(f.y); r.z = f2bf(f.z); r.w = f2bf(f.w);
    *(ushort4*)o = r;
  } else {
    int idx = (bid - 1536) * 256 + t;
    float4 z = {0.f, 0.f, 0.f, 0.f};
    *(float4*)(rowsum + idx * 8) = z;
    *(float4*)(rowsum + idx * 8 + 4) = z;
  }
}

// ------- apply groupnorm + transpose (per-block AB recompute) -------------
__global__ __launch_bounds__(256) void gn_apply_t(const float* __restrict__ x,
                                                  const float2* __restrict__ part,
                                                  const float* __restrict__ gamma,
                                                  const float* __restrict__ beta,
                                                  u16* __restrict__ hnt) {
  int p0 = blockIdx.x * 32, c0 = blockIdx.y * 32, b = blockIdx.z;
  __shared__ float tile[32][33];
  __shared__ float2 ABs[32];
  int t = threadIdx.x;
  if (t < 32) {
    int c = c0 + t;
    int g = (b * 512 + c) >> 4;  // global 16-channel group
    float s = 0.f, q = 0.f;
#pragma unroll
    for (int j = 0; j < 8; ++j) {
      float2 pp = part[g * 8 + j];
      s += pp.x; q += pp.y;
    }
    float mean = s * (1.0f / 65536.0f);
    float var = q * (1.0f / 65536.0f) - mean * mean;
    float a = gamma[c] * rsqrtf(var + 1e-6f);
    ABs[t] = make_float2(a, beta[c] - mean * a);
  }
  const float* xb = x + (long)b * 2097152;
#pragma unroll
  for (int j = 0; j < 4; ++j) {
    int lc = (t >> 5) + j * 8, lp = t & 31;
    tile[lc][lp] = xb[(long)(c0 + lc) * 4096 + p0 + lp];
  }
  __syncthreads();
#pragma unroll
  for (int j = 0; j < 4; ++j) {
    int lp = (t >> 5) + j * 8, lc = t & 31;
    float2 ab = ABs[lc];
    float val = tile[lc][lp] * ab.x + ab.y;
    hnt[(long)b * 2097152 + (long)(p0 + lp) * 512 + c0 + lc] = f2bf(val);
  }
}

// ------- split-K4 reduce + rowsum normalize -> out_t (bf16) ---------------
__global__ __launch_bounds__(256) void reduce_pv4(const u16* __restrict__ parts,
                                                  u16* __restrict__ out,
                                                  const float* __restrict__ rowsum) {
  long i = ((long)blockIdx.x * 256 + threadIdx.x) * 8;  // [0, 4194304)
  long b = i >> 21, off = i & 2097151;
  const u16* base = parts + b * 8388608 + off;
  float inv = 1.0f / rowsum[b * 4096 + (off >> 9)];
  s8v a = *(const s8v*)(base);
  s8v bb = *(const s8v*)(base + 2097152);
  s8v c = *(const s8v*)(base + 4194304);
  s8v d = *(const s8v*)(base + 6291456);
  s8v o;
#pragma unroll
  for (int j = 0; j < 8; ++j)
    o[j] = (short)f2bf((bf2f((u16)a[j]) + bf2f((u16)bb[j]) + bf2f((u16)c[j]) +
                        bf2f((u16)d[j])) * inv);
  *(s8v*)(out + i) = o;
}

// ---------------- fused QKV GEMM: q,k,v all written fp8 (k-interleaved) ---
__global__ __launch_bounds__(256) void gemm_qkv3(
    const u16* __restrict__ hnt, const u16* __restrict__ wqb,
    u8* __restrict__ q8, u8* __restrict__ k8, u8* __restrict__ v8,
    const float* __restrict__ bq, const float* __restrict__ bk,
    const float* __restrict__ bv) {
  constexpr int MI = 4, NI = 2, AGW = 2, NLD = 5;
  __shared__ __align__(16) u16 la[3][4096];
  __shared__ __align__(16) u16 lb[3][3][2048];
  const int t = threadIdx.x;
  const int lane = t & 63, wv = t >> 6;
  const int wm = wv >> 1, wn = wv & 1;

  int lin = blockIdx.x;
  int xcd = lin & 7, s = lin >> 3;
  int bn_i = s % 8, t2 = s / 8;
  int bm_i = (t2 % 4) * 8 + xcd;
  int bb = t2 / 4;
  const int bm = bm_i * 128, bn = bn_i * 64;

  const u16* A = hnt + (long)bb * 2097152;
  const u16* aP[AGW];
#pragma unroll
  for (int j = 0; j < AGW; ++j)
    aP[j] = A + (long)(bm + (wv + j * 4) * 16 + (lane & 15)) * 512 +
            (lane >> 4) * 8;
  const u16* bP[3];
#pragma unroll
  for (int w = 0; w < 3; ++w)
    bP[w] = wqb + (long)w * 262144 +
            (long)(bn + wv * 16 + (lane & 15)) * 512 + (lane >> 4) * 8;

  auto issue = [&](int buf) {
#pragma unroll
    for (int j = 0; j < AGW; ++j) {
      gload16(aP[j], &la[buf][(wv + j * 4) * 512 + lane * 8]);
      aP[j] += 32;
    }
#pragma unroll
    for (int w = 0; w < 3; ++w) {
      gload16(bP[w], &lb[buf][w][wv * 512 + lane * 8]);
      bP[w] += 32;
    }
  };

  f4v acc[3][MI][NI];
#pragma unroll
  for (int w = 0; w < 3; ++w)
#pragma unroll
    for (int i = 0; i < MI; ++i)
#pragma unroll
      for (int j = 0; j < NI; ++j) acc[w][i][j] = (f4v){0.f, 0.f, 0.f, 0.f};

  issue(0);
  issue(1);
  int cur = 0, nxt = 2;
  for (int it = 0; it < 16; ++it) {
    if (it < 15)
      asm volatile("s_waitcnt vmcnt(%0)" ::"n"(NLD) : "memory");
    else
      asm volatile("s_waitcnt vmcnt(0)" ::: "memory");
    asm volatile("s_barrier" ::: "memory");
    if (it + 2 < 16) issue(nxt);

    s8v af[MI], bfr[3][NI];
#pragma unroll
    for (int mi = 0; mi < MI; ++mi)
      af[mi] = *(const s8v*)&la[cur][((wm * MI + mi) * 64 + lane) * 8];
#pragma unroll
    for (int w = 0; w < 3; ++w)
#pragma unroll
      for (int ni = 0; ni < NI; ++ni)
        bfr[w][ni] =
            *(const s8v*)&lb[cur][w][((wn * NI + ni) * 64 + lane) * 8];
#pragma unroll
    for (int w = 0; w < 3; ++w)
#pragma unroll
      for (int mi = 0; mi < MI; ++mi)
#pragma unroll
        for (int ni = 0; ni < NI; ++ni)
          acc[w][mi][ni] = __builtin_amdgcn_mfma_f32_16x16x32_bf16(
              af[mi], bfr[w][ni], acc[w][mi][ni], 0, 0, 0);
    cur = cur == 2 ? 0 : cur + 1;
    nxt = nxt == 2 ? 0 : nxt + 1;
  }

  const int quad = lane >> 4, col = lane & 15;
#pragma unroll
  for (int w = 0; w < 3; ++w) {
    const float* bias = w == 0 ? bq : w == 1 ? bk : bv;
    u8* dst = w == 0 ? q8 : k8;
#pragma unroll
    for (int mi = 0; mi < MI; ++mi) {
#pragma unroll
      for (int ni = 0; ni < NI; ++ni) {
        int n = bn + wn * 32 + ni * 16 + col;
        int m0 = bm + wm * 64 + mi * 16 + quad * 4;
        f4v vv = acc[w][mi][ni];
        float bsv = bias[n];
        if (w == 2) {
          // v8[n][m]: permute pixel index m0 (4B store stays inside its
          // 8B block: m0 % 8 in {0,4})
          int mp = kperm(m0);
          *(unsigned*)&v8[(long)bb * 2097152 + (long)n * 4096 + mp] =
              pk4fp8(vv[0] + bsv, vv[1] + bsv, vv[2] + bsv, vv[3] + bsv);
        } else {
          // q8/k8[m][k=n]: permute channel index n
          int np = kperm(n);
#pragma unroll
          for (int r2 = 0; r2 < 4; ++r2)
            dst[(long)bb * 2097152 + (long)(m0 + r2) * 512 + np] =
                f2fp8(vv[r2] + bsv);
        }
      }
    }
  }
}

// ---------------- fp8 256x128-tile GEMM, pipelined fragment prefetch ------
// GM==0: P8 = exp(scale*q8.k8^T - 1) fp8 k-ilv + rowsum atomics.
//        M=4096 N=4096 K=512.                        grid 1024, 512 thr
// GM==1: parts = P8 . v8^T (unnormalized, split-K4)  grid 512, 512 thr
// 256x128 tile, BK=64, 8 waves (4Mx2N, wave 64x64), 3 LDS bufs of 24KB.
// Register-level software pipeline with CORRECT cross-wave ordering
// (r7's NaN: prefetch ds_read trusted per-wave vmcnt for block-wide
// staging).  Per K-step:
//   issue 3 staging gloads (kt+2 -> buf (kt+2)%3)
//   vmcnt(3)   -- my kt+1 loads landed (the 3 outstanding are kt+2's)
//   lgkmcnt(0) -- my frag reads of tile kt retired (WAR: buf kt%3 is the
//                 NEXT staging target after this barrier)
//   s_barrier  -- all waves' kt+1 staging landed + all reads retired
//   ds_read kt+1 frags -> spare reg set   (LDS pipe, overlaps MFMA)
//   MFMA kt from current reg set          (matrix pipe)
// One barrier per K-tile.  Frag regs double-buffered as named sets
// aX/bX <-> aY/bY (rule #20: no runtime-indexed frag arrays).
// launch_bounds(512,2): ~150 VGPR (acc 64 + 2x32 frags), cap 256.
template <int GM>
__global__ __launch_bounds__(512, 2) void gemm8p(const u8* __restrict__ Ag,
                                                 const u8* __restrict__ Bg,
                                                 u16* __restrict__ Dg,
                                                 float* __restrict__ rowsum) {
  constexpr int NKT = GM == 0 ? 8 : 16;
  constexpr long ld = GM == 0 ? 512 : 4096;  // A and B K-stride (bytes)
  constexpr int nx = GM == 0 ? 32 : 4;       // N tiles (128-wide)
  constexpr long ha = 128 * ld;              // A half-tile (128 rows)
  constexpr int BUF = 24576;
  __shared__ __align__(16) u8 lds[73728];

  const int t = threadIdx.x;
  const int lane = t & 63, wv = t >> 6;
  const int wm = wv >> 1, wn = wv & 1;

  int lin = blockIdx.x;
  int xcd = lin & 7, s = lin >> 3;
  int bn_i = s % nx, rest = s / nx;
  int bm_i = (rest & 1) * 8 + xcd, rest2 = rest >> 1;
  int ks = 0, b;
  if constexpr (GM == 1) {
    ks = rest2 & 3;
    b = rest2 >> 2;
  } else {
    b = rest2;
  }
  const int bm = bm_i * 256, bn = bn_i * 128;

  const u8* A = Ag + (long)b * (GM == 0 ? 2097152 : 16777216);
  const u8* B = Bg + (long)b * 2097152;
  const long k0 = GM == 1 ? (long)ks * 1024 : 0;

  // staging: thread t covers row (t>>2), 16B chunk (t&3); source chunk
  // pre-swizzled so LDS holds row[chunk ^ ((row>>1)&3)].
  const int tchunk = ((t & 3) ^ ((t >> 3) & 3)) * 16;
  const u8* pA0 = A + (long)(bm + (t >> 2)) * ld + k0 + tchunk;
  const u8* pB0 = B + (long)(bn + (t >> 2)) * ld + k0 + tchunk;

  // per-lane read constants: fragment row = lane&15, chunk = lane>>4
  const int r16 = lane & 15, q = lane >> 4;
  const int swz = (r16 >> 1) & 3;
  const int caq = (q ^ swz) * 16;
  const int aRow = (wm * 64 + r16) * 64;           // A zone [0,16384)
  const int bRow = 16384 + (wn * 64 + r16) * 64;   // B zone [16384,24576)

  f4v acc[4][4];
#pragma unroll
  for (int i = 0; i < 4; ++i)
#pragma unroll
    for (int j = 0; j < 4; ++j) acc[i][j] = (f4v){0.f, 0.f, 0.f, 0.f};

  // prologue: stage K-tiles 0,1 into bufs 0,1 (6 loads/thread)
#pragma unroll
  for (int T = 0; T < 2; ++T) {
    gload16(pA0 + T * 64, &lds[T * BUF + t * 16]);
    gload16(pA0 + ha + T * 64, &lds[T * BUF + 8192 + t * 16]);
    gload16(pB0 + T * 64, &lds[T * BUF + 16384 + t * 16]);
  }
  asm volatile("s_waitcnt vmcnt(3)" ::: "memory");  // tile 0 landed (mine)
  asm volatile("s_barrier" ::: "memory");           // ... and everyone's

  // prologue fragment reads: tile 0 from buf 0
  l2v aX[4], bX[4], aY[4], bY[4];
#pragma unroll
  for (int i = 0; i < 4; ++i) {
    aX[i] = *(const l2v*)(lds + aRow + i * 1024 + caq);
    bX[i] = *(const l2v*)(lds + bRow + i * 1024 + caq);
  }

  const u8* pA = pA0 + 128;  // tile kt+2 source
  const u8* pB = pB0 + 128;
  int kt = 0, nxt = 1, nbuf = 2;

#define STEP(AC, BC, AN, BN_)                                               \
  {                                                                         \
    const bool st = kt <= NKT - 3;                                          \
    u8* SB = &lds[nbuf * BUF];                                              \
    if (st) {                                                               \
      gload16(pA, SB + t * 16);                                             \
      gload16(pA + ha, SB + 8192 + t * 16);                                 \
      gload16(pB, SB + 16384 + t * 16);                                     \
    }                                                                       \
    if (kt < NKT - 1) {                                                     \
      if (st)                                                               \
        asm volatile("s_waitcnt vmcnt(3)" ::: "memory");                    \
      else                                                                  \
        asm volatile("s_waitcnt vmcnt(0)" ::: "memory");                    \
      asm volatile("s_waitcnt lgkmcnt(0)" ::: "memory");                    \
      asm volatile("s_barrier" ::: "memory");                               \
      const u8* LN = &lds[nxt * BUF];                                       \
      _Pragma("unroll") for (int i = 0; i < 4; ++i) {                       \
        AN[i] = *(const l2v*)(LN + aRow + i * 1024 + caq);                  \
        BN_[i] = *(const l2v*)(LN + bRow + i * 1024 + caq);                 \
      }                                                                     \
    }                                                                       \
    __builtin_amdgcn_s_setprio(1);                                          \
    _Pragma("unroll") for (int mi = 0; mi < 4; ++mi)                        \
        _Pragma("unroll") for (int ni = 0; ni < 4; ++ni) {                  \
      acc[mi][ni] = __builtin_amdgcn_mfma_f32_16x16x32_fp8_fp8(             \
          AC[mi][0], BC[ni][0], acc[mi][ni], 0, 0, 0);                      \
      acc[mi][ni] = __builtin_amdgcn_mfma_f32_16x16x32_fp8_fp8(             \
          AC[mi][1], BC[ni][1], acc[mi][ni], 0, 0, 0);                      \
    }                                                                       \
    __builtin_amdgcn_s_setprio(0);                                          \
    pA += 64;                                                               \
    pB += 64;                                                               \
    ++kt;                                                                   \
    nxt = nxt == 2 ? 0 : nxt + 1;                                           \
    nbuf = nbuf == 2 ? 0 : nbuf + 1;                                        \
  }

  for (int it2 = 0; it2 < NKT / 2; ++it2) {
    STEP(aX, bX, aY, bY)
    STEP(aY, bY, aX, bX)
  }
#undef STEP

  if constexpr (GM == 0) {
    // epilogue: E = exp(S*scale - 1) -> LDS pack -> coalesced fp8 stores,
    // plus per-row sums -> LDS -> one atomicAdd per row per block.
    const float qk = 0.044194173824159216f;
    u8* Pb = (u8*)Dg + (long)b * 16777216;
    __syncthreads();  // all K-loop LDS reads done; reuse lds
    u8* zone = lds + wv * 4096;            // [64 rows][64B], q-xor swizzled
    float* rs = (float*)(lds + 32768);     // [2][256] f32
#pragma unroll
    for (int mi = 0; mi < 4; ++mi) {
      f4v sum4 = (f4v){0.f, 0.f, 0.f, 0.f};
#pragma unroll
      for (int ni = 0; ni < 4; ++ni) {
        int np = kperm(ni * 16 + r16);
        f4v vv = acc[mi][ni];
#pragma unroll
        for (int r2 = 0; r2 < 4; ++r2) {
          float e = __expf(vv[r2] * qk - 1.0f);
          zone[(mi * 16 + q * 4 + r2) * 64 + (np ^ (q << 4))] = f2fp8(e);
          sum4[r2] += e;
        }
      }
#pragma unroll
      for (int o = 8; o; o >>= 1) {
        sum4[0] += __shfl_xor(sum4[0], o, 64);
        sum4[1] += __shfl_xor(sum4[1], o, 64);
        sum4[2] += __shfl_xor(sum4[2], o, 64);
        sum4[3] += __shfl_xor(sum4[3], o, 64);
      }
      if (r16 == 0)
        *(float4*)&rs[wn * 256 + wm * 64 + mi * 16 + q * 4] =
            make_float4(sum4[0], sum4[1], sum4[2], sum4[3]);
    }
    __syncthreads();
#pragma unroll
    for (int i = 0; i < 4; ++i) {
      int zr = i * 16 + (lane >> 2);
      int pc = (lane & 3) ^ ((lane >> 4) & 3);
      uint4 vvv = *(const uint4*)(zone + zr * 64 + pc * 16);
      *(uint4*)(Pb + (long)(bm + wm * 64 + zr) * 4096 + bn + wn * 64 +
                (lane & 3) * 16) = vvv;
    }
    if (t < 256)
      atomicAdd(&rowsum[(long)b * 4096 + bm + t], rs[t] + rs[256 + t]);
  } else {
    // epilogue: unnormalized PV partial -> bf16
    u16* D = Dg + (long)b * 8388608 + (long)ks * 2097152;
#pragma unroll
    for (int mi = 0; mi < 4; ++mi) {
      int m0 = bm + wm * 64 + mi * 16 + q * 4;
#pragma unroll
      for (int ni = 0; ni < 4; ++ni) {
        int n = bn + wn * 64 + ni * 16 + r16;
        f4v vv = acc[mi][ni];
#pragma unroll
        for (int r2 = 0; r2 < 4; ++r2)
          D[(long)(m0 + r2) * 512 + n] = f2bf(vv[r2]);
      }
    }
  }
  (void)rowsum;
}

// ---------------- bf16 NT GEMM (FINAL) ------------------------------------
template <int MODE, int BM, int BN>
__global__ __launch_bounds__(256) void gemm_nt(
    const u16* __restrict__ Ag, long sA, const u16* __restrict__ Btg, long sB,
    void* __restrict__ Cg, long sC, int nx, int nyg, int K, long lda, long ldb,
    int N, const float* __restrict__ b0, const float* __restrict__ resid,
    long sR, float scale) {
  constexpr int MI = BM / 32, NI = BN / 32;
  constexpr int AGW = BM / 64, BGW = BN / 64;
  constexpr int NLD = AGW + BGW;
  __shared__ __align__(16) u16 lds_a[3][BM * 32];
  __shared__ __align__(16) u16 lds_b[3][BN * 32];
  const int t = threadIdx.x;
  const int lane = t & 63, wv = t >> 6;
  const int wm = wv >> 1, wn = wv & 1;

  int lin = blockIdx.x;
  int xcd = lin & 7, s = lin >> 3;
  int bn_i = s % nx, t2 = s / nx;
  int bm_i = (t2 % nyg) * 8 + xcd;
  int bz = t2 / nyg;

  const u16* A = Ag + (long)bz * sA;
  const u16* Bt = Btg + (long)bz * sB;
  long c_off = (long)bz * sC;
  const int bm = bm_i * BM, bn = bn_i * BN;

  const u16* aP[AGW];
  const u16* bP[BGW];
#pragma unroll
  for (int j = 0; j < AGW; ++j)
    aP[j] = A + (long)(bm + (wv + j * 4) * 16 + (lane & 15)) * lda +
            (lane >> 4) * 8;
#pragma unroll
  for (int j = 0; j < BGW; ++j)
    bP[j] = Bt + (long)(bn + (wv + j * 4) * 16 + (lane & 15)) * ldb +
            (lane >> 4) * 8;

  auto issue = [&](int buf) {
#pragma unroll
    for (int j = 0; j < AGW; ++j) {
      gload16(aP[j], &lds_a[buf][(wv + j * 4) * 512 + lane * 8]);
      aP[j] += 32;
    }
#pragma unroll
    for (int j = 0; j < BGW; ++j) {
      gload16(bP[j], &lds_b[buf][(wv + j * 4) * 512 + lane * 8]);
      bP[j] += 32;
    }
  };

  f4v acc[MI][NI];
#pragma unroll
  for (int i = 0; i < MI; ++i)
#pragma unroll
    for (int j = 0; j < NI; ++j) acc[i][j] = (f4v){0.f, 0.f, 0.f, 0.f};

  const int NIT = K / 32;
  issue(0);
  issue(1);
  int cur = 0, nxt = 2;
  for (int it = 0; it < NIT; ++it) {
    if (it < NIT - 1)
      asm volatile("s_waitcnt vmcnt(%0)" ::"n"(NLD) : "memory");
    else
      asm volatile("s_waitcnt vmcnt(0)" ::: "memory");
    asm volatile("s_barrier" ::: "memory");
    if (it + 2 < NIT) issue(nxt);

    s8v af[MI], bfr[NI];
#pragma unroll
    for (int mi = 0; mi < MI; ++mi)
      af[mi] = *(const s8v*)&lds_a[cur][((wm * MI + mi) * 64 + lane) * 8];
#pragma unroll
    for (int ni = 0; ni < NI; ++ni)
      bfr[ni] = *(const s8v*)&lds_b[cur][((wn * NI + ni) * 64 + lane) * 8];
#pragma unroll
    for (int mi = 0; mi < MI; ++mi)
#pragma unroll
      for (int ni = 0; ni < NI; ++ni)
        acc[mi][ni] = __builtin_amdgcn_mfma_f32_16x16x32_bf16(
            af[mi], bfr[ni], acc[mi][ni], 0, 0, 0);
    cur = cur == 2 ? 0 : cur + 1;
    nxt = nxt == 2 ? 0 : nxt + 1;
  }

  const int quad = lane >> 4, col = lane & 15;
#pragma unroll
  for (int mi = 0; mi < MI; ++mi) {
#pragma unroll
    for (int ni = 0; ni < NI; ++ni) {
      int n = bn + wn * (BN / 2) + ni * 16 + col;
      int m0 = bm + wm * (BM / 2) + mi * 16 + quad * 4;
      f4v vv = acc[mi][ni];
#pragma unroll
      for (int r2 = 0; r2 < 4; ++r2) {
        int m = m0 + r2;
        float val = vv[r2];
        if constexpr (MODE == MODE_SCALE) val *= scale;
        if constexpr (MODE == MODE_FINAL) {
          val += b0[m] + resid[(long)bz * sR + (long)m * N + n];
          ((float*)Cg)[c_off + (long)m * N + n] = val;
        } else {
          ((u16*)Cg)[c_off + (long)m * N + n] = f2bf(val);
        }
      }
    }
  }
  (void)scale; (void)resid;
}

extern "C" void kernel_launch(void* const* d_in, const int* in_sizes, int n_in,
                              void* d_out, int out_size, void* d_ws,
                              size_t ws_size, hipStream_t stream) {
  const float* x = (const float*)d_in[0];
  const float* gamma = (const float*)d_in[1];
  const float* beta = (const float*)d_in[2];
  const float* wq = (const float*)d_in[3];
  const float* bq = (const float*)d_in[4];
  const float* wk = (const float*)d_in[5];
  const float* bk = (const float*)d_in[6];
  const float* wv = (const float*)d_in[7];
  const float* bv = (const float*)d_in[8];
  const float* wo = (const float*)d_in[9];
  const float* bo = (const float*)d_in[10];

  // ws_size = 256 MiB (observed: harness poison fill writes 262144 KB).
  u8* wsb = (u8*)d_ws;
  u16* hnt = (u16*)wsb;                  // 8M: hn^t bf16; later out_t
  u8* q8 = wsb + 8388608;                // 4M fp8 [2][4096][512] k-interleaved
  u8* k8 = wsb + 12582912;               // 4M
  u8* v8 = wsb + 16777216;               // 4M fp8 [2][512][4096] k-interleaved
  u16* wqb = (u16*)(wsb + 20971520);     // 2M: 4 weights bf16
  u16* wob = wqb + 786432;
  float2* part = (float2*)(wsb + 23068672);
  float* rowsum = (float*)(wsb + 25165824);  // 32K: [2][4096] f32
  u8* P8 = wsb + 92274688;               // 32M: [2][4096][4096] fp8 k-ilv
  u16* parts = (u16*)(wsb + 125829120);  // 32M: [2][4][4096][512] bf16

  // stats + weight cast + rowsum zero: one fat kernel
  prep<<<1540, 256, 0, stream>>>(x, wq, wk, wv, wo, part, wqb, rowsum);
  // groupnorm apply + transpose (AB recomputed per block from part)
  gn_apply_t<<<dim3(128, 16, 2), 256, 0, stream>>>(x, part, gamma, beta, hnt);

  // fused q/k/v (all fp8, k-interleaved): 512 blocks
  gemm_qkv3<<<512, 256, 0, stream>>>(hnt, wqb, q8, k8, v8, bq, bk, bv);

  // P8 = exp(scale * q8 k8^T - 1) + rowsum atomics: 1024 blocks (256x128)
  gemm8p<0><<<1024, 512, 0, stream>>>(q8, k8, (u16*)P8, rowsum);
  // PV fp8 split-K4 (unnormalized), both batches: 512 blocks (256x128)
  gemm8p<1><<<512, 512, 0, stream>>>(P8, v8, parts, rowsum);
  // out_t = (sum of 4 partials) / rowsum, both batches
  reduce_pv4<<<2048, 256, 0, stream>>>(parts, hnt, rowsum);

  // d_out = wo . out_t^T + bo + x: 64x128, nx=32, nyg=1, nz=2 -> 512 blocks
  gemm_nt<MODE_FINAL, 64, 128><<<512, 256, 0, stream>>>(
      wob, 0, hnt, 2097152, d_out, 2097152, 32, 1, 512, 512, 512, 4096, bo,
      x, 2097152, 0.f);

  (void)in_sizes; (void)n_in; (void)out_size; (void)ws_size;
}

// Round 9
// 204.978 us; speedup vs baseline: 1.0336x; 1.0336x over previous
//
#include <hip/hip_runtime.h>

typedef unsigned short u16;
typedef unsigned char u8;
typedef __attribute__((ext_vector_type(8))) short s8v;
typedef __attribute__((ext_vector_type(4))) float f4v;
typedef __attribute__((ext_vector_type(2))) long l2v;

enum { MODE_SCALE = 2, MODE_FINAL = 3 };

__device__ __forceinline__ u16 f2bf(float f) {
  unsigned u = __builtin_bit_cast(unsigned, f);
  u += 0x7fffu + ((u >> 16) & 1u);
  return (u16)(u >> 16);
}
__device__ __forceinline__ float bf2f(u16 h) {
  unsigned u = ((unsigned)h) << 16;
  return __builtin_bit_cast(float, u);
}
__device__ __forceinline__ void gload16(const void* g, void* l) {
  __builtin_amdgcn_global_load_lds(
      (const __attribute__((address_space(1))) unsigned int*)g,
      (__attribute__((address_space(3))) unsigned int*)l, 16, 0, 0);
}
__device__ __forceinline__ unsigned pk4fp8(float a, float b, float c, float d) {
  int lo = __builtin_amdgcn_cvt_pk_fp8_f32(a, b, 0, false);
  return (unsigned)__builtin_amdgcn_cvt_pk_fp8_f32(c, d, lo, true);
}
__device__ __forceinline__ u8 f2fp8(float a) {
  return (u8)(__builtin_amdgcn_cvt_pk_fp8_f32(a, a, 0, false) & 0xff);
}
// k-interleave permutation within each aligned 64B k-group: byte j ->
// ((j>>3)&3)*16 + ((j>>5)&1)*8 + (j&7).  Chunk q (16B) of a row then holds
// [k 8q..8q+7][k 32+8q..32+8q+7] = both MFMA k-slices for lane quad q.
__device__ __forceinline__ int kperm(int j) {
  return (j & ~63) | (((j >> 3) & 3) << 4) | (((j >> 5) & 1) << 3) | (j & 7);
}

// ------- prep fat kernel: gn partial stats + weight->bf16 + zeroing -------
// blocks [0,512):    gn_stats (x partial sums, 2 channels/block)
// blocks [512,1536): w2bf (4 weight matrices -> bf16)
// blocks [1536,1540): zero rowsum (2x4096 f32)
__global__ __launch_bounds__(256) void prep(
    const float* __restrict__ x, const float* __restrict__ w0,
    const float* __restrict__ w1, const float* __restrict__ w2,
    const float* __restrict__ w3, float2* __restrict__ part,
    u16* __restrict__ wout, float* __restrict__ rowsum) {
  const int bid = blockIdx.x;
  const int t = threadIdx.x;
  if (bid < 512) {
    const float4* p4 = (const float4*)(x + (long)bid * 8192);
    float s = 0.f, q = 0.f;
#pragma unroll
    for (int j = 0; j < 8; ++j) {
      float4 f = p4[t + 256 * j];
      s += f.x + f.y + f.z + f.w;
      q += f.x * f.x + f.y * f.y + f.z * f.z + f.w * f.w;
    }
#pragma unroll
    for (int o = 32; o; o >>= 1) {
      s += __shfl_xor(s, o, 64);
      q += __shfl_xor(q, o, 64);
    }
    __shared__ float rs[4], rq[4];
    int lane = t & 63, wv = t >> 6;
    if (lane == 0) { rs[wv] = s; rq[wv] = q; }
    __syncthreads();
    if (t == 0)
      part[bid] = make_float2(rs[0] + rs[1] + rs[2] + rs[3],
                              rq[0] + rq[1] + rq[2] + rq[3]);
  } else if (bid < 1536) {
    int wb = bid - 512;
    int which = wb >> 8;
    const float* w = which == 0 ? w0 : which == 1 ? w1 : which == 2 ? w2 : w3;
    int i = ((wb & 255) * 256 + t) * 4;
    float4 f = *(const float4*)(w + i);
    u16* o = wout + (long)which * 262144 + i;
    ushort4 r;
    r.x = f2bf(f.x); r.y = f2bf(f.y); r.z = f2bf(f.z); r.w = f2bf(f.w);
    *(ushort4*)o = r;
  } else {
    int idx = (bid - 1536) * 256 + t;
    float4 z = {0.f, 0.f, 0.f, 0.f};
    *(float4*)(rowsum + idx * 8) = z;
    *(float4*)(rowsum + idx * 8 + 4) = z;
  }
}

// ------- apply groupnorm + transpose (per-block AB recompute) -------------
__global__ __launch_bounds__(256) void gn_apply_t(const float* __restrict__ x,
                                                  const float2* __restrict__ part,
                                                  const float* __restrict__ gamma,
                                                  const float* __restrict__ beta,
                                                  u16* __restrict__ hnt) {
  int p0 = blockIdx.x * 32, c0 = blockIdx.y * 32, b = blockIdx.z;
  __shared__ float tile[32][33];
  __shared__ float2 ABs[32];
  int t = threadIdx.x;
  if (t < 32) {
    int c = c0 + t;
    int g = (b * 512 + c) >> 4;  // global 16-channel group
    float s = 0.f, q = 0.f;
#pragma unroll
    for (int j = 0; j < 8; ++j) {
      float2 pp = part[g * 8 + j];
      s += pp.x; q += pp.y;
    }
    float mean = s * (1.0f / 65536.0f);
    float var = q * (1.0f / 65536.0f) - mean * mean;
    float a = gamma[c] * rsqrtf(var + 1e-6f);
    ABs[t] = make_float2(a, beta[c] - mean * a);
  }
  const float* xb = x + (long)b * 2097152;
#pragma unroll
  for (int j = 0; j < 4; ++j) {
    int lc = (t >> 5) + j * 8, lp = t & 31;
    tile[lc][lp] = xb[(long)(c0 + lc) * 4096 + p0 + lp];
  }
  __syncthreads();
#pragma unroll
  for (int j = 0; j < 4; ++j) {
    int lp = (t >> 5) + j * 8, lc = t & 31;
    float2 ab = ABs[lc];
    float val = tile[lc][lp] * ab.x + ab.y;
    hnt[(long)b * 2097152 + (long)(p0 + lp) * 512 + c0 + lc] = f2bf(val);
  }
}

// ------- split-K2 reduce + rowsum normalize -> out_t (bf16) ---------------
__global__ __launch_bounds__(256) void reduce_pv2(const u16* __restrict__ parts,
                                                  u16* __restrict__ out,
                                                  const float* __restrict__ rowsum) {
  long i = ((long)blockIdx.x * 256 + threadIdx.x) * 8;  // [0, 4194304)
  long b = i >> 21, off = i & 2097151;
  const u16* base = parts + b * 4194304 + off;
  float inv = 1.0f / rowsum[b * 4096 + (off >> 9)];
  s8v a = *(const s8v*)(base);
  s8v bb = *(const s8v*)(base + 2097152);
  s8v o;
#pragma unroll
  for (int j = 0; j < 8; ++j)
    o[j] = (short)f2bf((bf2f((u16)a[j]) + bf2f((u16)bb[j])) * inv);
  *(s8v*)(out + i) = o;
}

// ---------------- fused QKV GEMM: q,k,v all written fp8 (k-interleaved) ---
__global__ __launch_bounds__(256) void gemm_qkv3(
    const u16* __restrict__ hnt, const u16* __restrict__ wqb,
    u8* __restrict__ q8, u8* __restrict__ k8, u8* __restrict__ v8,
    const float* __restrict__ bq, const float* __restrict__ bk,
    const float* __restrict__ bv) {
  constexpr int MI = 4, NI = 2, AGW = 2, NLD = 5;
  __shared__ __align__(16) u16 la[3][4096];
  __shared__ __align__(16) u16 lb[3][3][2048];
  const int t = threadIdx.x;
  const int lane = t & 63, wv = t >> 6;
  const int wm = wv >> 1, wn = wv & 1;

  int lin = blockIdx.x;
  int xcd = lin & 7, s = lin >> 3;
  int bn_i = s % 8, t2 = s / 8;
  int bm_i = (t2 % 4) * 8 + xcd;
  int bb = t2 / 4;
  const int bm = bm_i * 128, bn = bn_i * 64;

  const u16* A = hnt + (long)bb * 2097152;
  const u16* aP[AGW];
#pragma unroll
  for (int j = 0; j < AGW; ++j)
    aP[j] = A + (long)(bm + (wv + j * 4) * 16 + (lane & 15)) * 512 +
            (lane >> 4) * 8;
  const u16* bP[3];
#pragma unroll
  for (int w = 0; w < 3; ++w)
    bP[w] = wqb + (long)w * 262144 +
            (long)(bn + wv * 16 + (lane & 15)) * 512 + (lane >> 4) * 8;

  auto issue = [&](int buf) {
#pragma unroll
    for (int j = 0; j < AGW; ++j) {
      gload16(aP[j], &la[buf][(wv + j * 4) * 512 + lane * 8]);
      aP[j] += 32;
    }
#pragma unroll
    for (int w = 0; w < 3; ++w) {
      gload16(bP[w], &lb[buf][w][wv * 512 + lane * 8]);
      bP[w] += 32;
    }
  };

  f4v acc[3][MI][NI];
#pragma unroll
  for (int w = 0; w < 3; ++w)
#pragma unroll
    for (int i = 0; i < MI; ++i)
#pragma unroll
      for (int j = 0; j < NI; ++j) acc[w][i][j] = (f4v){0.f, 0.f, 0.f, 0.f};

  issue(0);
  issue(1);
  int cur = 0, nxt = 2;
  for (int it = 0; it < 16; ++it) {
    if (it < 15)
      asm volatile("s_waitcnt vmcnt(%0)" ::"n"(NLD) : "memory");
    else
      asm volatile("s_waitcnt vmcnt(0)" ::: "memory");
    asm volatile("s_barrier" ::: "memory");
    if (it + 2 < 16) issue(nxt);

    s8v af[MI], bfr[3][NI];
#pragma unroll
    for (int mi = 0; mi < MI; ++mi)
      af[mi] = *(const s8v*)&la[cur][((wm * MI + mi) * 64 + lane) * 8];
#pragma unroll
    for (int w = 0; w < 3; ++w)
#pragma unroll
      for (int ni = 0; ni < NI; ++ni)
        bfr[w][ni] =
            *(const s8v*)&lb[cur][w][((wn * NI + ni) * 64 + lane) * 8];
#pragma unroll
    for (int w = 0; w < 3; ++w)
#pragma unroll
      for (int mi = 0; mi < MI; ++mi)
#pragma unroll
        for (int ni = 0; ni < NI; ++ni)
          acc[w][mi][ni] = __builtin_amdgcn_mfma_f32_16x16x32_bf16(
              af[mi], bfr[w][ni], acc[w][mi][ni], 0, 0, 0);
    cur = cur == 2 ? 0 : cur + 1;
    nxt = nxt == 2 ? 0 : nxt + 1;
  }

  const int quad = lane >> 4, col = lane & 15;
#pragma unroll
  for (int w = 0; w < 3; ++w) {
    const float* bias = w == 0 ? bq : w == 1 ? bk : bv;
    u8* dst = w == 0 ? q8 : k8;
#pragma unroll
    for (int mi = 0; mi < MI; ++mi) {
#pragma unroll
      for (int ni = 0; ni < NI; ++ni) {
        int n = bn + wn * 32 + ni * 16 + col;
        int m0 = bm + wm * 64 + mi * 16 + quad * 4;
        f4v vv = acc[w][mi][ni];
        float bsv = bias[n];
        if (w == 2) {
          // v8[n][m]: permute pixel index m0 (4B store stays inside its
          // 8B block: m0 % 8 in {0,4})
          int mp = kperm(m0);
          *(unsigned*)&v8[(long)bb * 2097152 + (long)n * 4096 + mp] =
              pk4fp8(vv[0] + bsv, vv[1] + bsv, vv[2] + bsv, vv[3] + bsv);
        } else {
          // q8/k8[m][k=n]: permute channel index n
          int np = kperm(n);
#pragma unroll
          for (int r2 = 0; r2 < 4; ++r2)
            dst[(long)bb * 2097152 + (long)(m0 + r2) * 512 + np] =
                f2fp8(vv[r2] + bsv);
        }
      }
    }
  }
}

// ---------------- fp8 256x128-tile GEMM, 1 barrier / K-tile ---------------
// GM==0: P8 = exp(scale*q8.k8^T - 1) fp8 k-ilv + rowsum atomics.
//        M=4096 N=4096 K=512.                        grid 1024, 512 thr
// GM==1: parts = P8 . v8^T (unnormalized, split-K2)  grid 256, 512 thr
// 256x128 tile, BK=64, 8 waves, 3 LDS buffers of 24KB (72KB -> 2 blocks/CU).
// Inputs k-interleaved (kperm): one ds_read_b128 per fragment pair; chunk
// swizzle (r16>>1)&3 keeps reads bank-conflict-free.  One s_barrier per
// K-tile; counted vmcnt(3) gate (3 staging loads/thread/tile).
// NOTE: body/signature must stay EXACTLY this r6-verified form — r5's
// finisher graft flipped regalloc to VGPR=64 (acc spilled, 5.3x); r8's
// (512,2) reg-pipeline dropped to 1 block/CU (211.9us).  Keep (512,4).
template <int GM>
__global__ __launch_bounds__(512, 4) void gemm8p(const u8* __restrict__ Ag,
                                                 const u8* __restrict__ Bg,
                                                 u16* __restrict__ Dg,
                                                 float* __restrict__ rowsum) {
  constexpr int NKT = GM == 0 ? 8 : 32;
  constexpr long ld = GM == 0 ? 512 : 4096;  // A and B K-stride (bytes)
  constexpr int nx = GM == 0 ? 32 : 4;       // N tiles (128-wide)
  constexpr long ha = 128 * ld;              // A half-tile (128 rows)
  constexpr int BUF = 24576;
  __shared__ __align__(16) u8 lds[73728];

  const int t = threadIdx.x;
  const int lane = t & 63, wv = t >> 6;
  const int wm = wv >> 1, wn = wv & 1;

  int lin = blockIdx.x;
  int xcd = lin & 7, s = lin >> 3;
  int bn_i = s % nx, rest = s / nx;
  int bm_i = (rest & 1) * 8 + xcd, rest2 = rest >> 1;
  int ks = 0, b;
  if constexpr (GM == 1) {
    ks = rest2 & 1;
    b = rest2 >> 1;
  } else {
    b = rest2;
  }
  const int bm = bm_i * 256, bn = bn_i * 128;

  const u8* A = Ag + (long)b * (GM == 0 ? 2097152 : 16777216);
  const u8* B = Bg + (long)b * 2097152;
  const long k0 = GM == 1 ? (long)ks * 2048 : 0;

  // staging: thread t covers row (t>>2), 16B chunk (t&3); source chunk
  // pre-swizzled so LDS holds row[chunk ^ ((row>>1)&3)].
  const int tchunk = ((t & 3) ^ ((t >> 3) & 3)) * 16;
  const u8* pA0 = A + (long)(bm + (t >> 2)) * ld + k0 + tchunk;
  const u8* pB0 = B + (long)(bn + (t >> 2)) * ld + k0 + tchunk;

  // per-lane read constants: fragment row = lane&15, chunk = lane>>4
  const int r16 = lane & 15, q = lane >> 4;
  const int swz = (r16 >> 1) & 3;
  const int caq = (q ^ swz) * 16;
  const int aRow = (wm * 64 + r16) * 64;           // A zone [0,16384)
  const int bRow = 16384 + (wn * 64 + r16) * 64;   // B zone [16384,24576)

  f4v acc[4][4];
#pragma unroll
  for (int i = 0; i < 4; ++i)
#pragma unroll
    for (int j = 0; j < 4; ++j) acc[i][j] = (f4v){0.f, 0.f, 0.f, 0.f};

  // prologue: stage K-tiles 0,1 into bufs 0,1 (6 loads/thread)
#pragma unroll
  for (int T = 0; T < 2; ++T) {
    gload16(pA0 + T * 64, &lds[T * BUF + t * 16]);
    gload16(pA0 + ha + T * 64, &lds[T * BUF + 8192 + t * 16]);
    gload16(pB0 + T * 64, &lds[T * BUF + 16384 + t * 16]);
  }
  asm volatile("s_waitcnt vmcnt(3)" ::: "memory");  // tile 0 landed
  asm volatile("s_barrier" ::: "memory");

  int cur = 0, nbuf = 2;
  const u8* pA = pA0 + 128;  // tile kt+2 source
  const u8* pB = pB0 + 128;
  for (int kt = 0; kt < NKT; ++kt) {
    const u8* LA = &lds[cur * BUF];
    u8* SB = &lds[nbuf * BUF];
    const bool st = kt <= NKT - 3;

    l2v af[4], bfv[4];
#pragma unroll
    for (int mi = 0; mi < 4; ++mi)
      af[mi] = *(const l2v*)(LA + aRow + mi * 1024 + caq);
#pragma unroll
    for (int ni = 0; ni < 4; ++ni)
      bfv[ni] = *(const l2v*)(LA + bRow + ni * 1024 + caq);

    if (st) gload16(pA, SB + t * 16);
    __builtin_amdgcn_s_setprio(1);
#pragma unroll
    for (int mi = 0; mi < 2; ++mi)
#pragma unroll
      for (int ni = 0; ni < 4; ++ni) {
        acc[mi][ni] = __builtin_amdgcn_mfma_f32_16x16x32_fp8_fp8(
            af[mi][0], bfv[ni][0], acc[mi][ni], 0, 0, 0);
        acc[mi][ni] = __builtin_amdgcn_mfma_f32_16x16x32_fp8_fp8(
            af[mi][1], bfv[ni][1], acc[mi][ni], 0, 0, 0);
      }
    __builtin_amdgcn_s_setprio(0);
    if (st) gload16(pA + ha, SB + 8192 + t * 16);
    __builtin_amdgcn_s_setprio(1);
#pragma unroll
    for (int mi = 2; mi < 4; ++mi)
#pragma unroll
      for (int ni = 0; ni < 4; ++ni) {
        acc[mi][ni] = __builtin_amdgcn_mfma_f32_16x16x32_fp8_fp8(
            af[mi][0], bfv[ni][0], acc[mi][ni], 0, 0, 0);
        acc[mi][ni] = __builtin_amdgcn_mfma_f32_16x16x32_fp8_fp8(
            af[mi][1], bfv[ni][1], acc[mi][ni], 0, 0, 0);
      }
    __builtin_amdgcn_s_setprio(0);
    if (st) gload16(pB, SB + 16384 + t * 16);

    if (kt < NKT - 1) {
      if (st)
        asm volatile("s_waitcnt vmcnt(3)" ::: "memory");
      else
        asm volatile("s_waitcnt vmcnt(0)" ::: "memory");
      asm volatile("s_barrier" ::: "memory");
    }
    pA += 64;
    pB += 64;
    cur = cur == 2 ? 0 : cur + 1;
    nbuf = nbuf == 2 ? 0 : nbuf + 1;
  }

  if constexpr (GM == 0) {
    // epilogue: E = exp(S*scale - 1) -> LDS pack -> coalesced fp8 stores,
    // plus per-row sums -> LDS -> one atomicAdd per row per block.
    const float qk = 0.044194173824159216f;
    u8* Pb = (u8*)Dg + (long)b * 16777216;
    __syncthreads();  // all K-loop LDS reads done; reuse lds
    u8* zone = lds + wv * 4096;            // [64 rows][64B], q-xor swizzled
    float* rs = (float*)(lds + 32768);     // [2][256] f32
#pragma unroll
    for (int mi = 0; mi < 4; ++mi) {
      f4v sum4 = (f4v){0.f, 0.f, 0.f, 0.f};
#pragma unroll
      for (int ni = 0; ni < 4; ++ni) {
        int np = kperm(ni * 16 + r16);
        f4v vv = acc[mi][ni];
#pragma unroll
        for (int r2 = 0; r2 < 4; ++r2) {
          float e = __expf(vv[r2] * qk - 1.0f);
          zone[(mi * 16 + q * 4 + r2) * 64 + (np ^ (q << 4))] = f2fp8(e);
          sum4[r2] += e;
        }
      }
#pragma unroll
      for (int o = 8; o; o >>= 1) {
        sum4[0] += __shfl_xor(sum4[0], o, 64);
        sum4[1] += __shfl_xor(sum4[1], o, 64);
        sum4[2] += __shfl_xor(sum4[2], o, 64);
        sum4[3] += __shfl_xor(sum4[3], o, 64);
      }
      if (r16 == 0)
        *(float4*)&rs[wn * 256 + wm * 64 + mi * 16 + q * 4] =
            make_float4(sum4[0], sum4[1], sum4[2], sum4[3]);
    }
    __syncthreads();
#pragma unroll
    for (int i = 0; i < 4; ++i) {
      int zr = i * 16 + (lane >> 2);
      int pc = (lane & 3) ^ ((lane >> 4) & 3);
      uint4 vvv = *(const uint4*)(zone + zr * 64 + pc * 16);
      *(uint4*)(Pb + (long)(bm + wm * 64 + zr) * 4096 + bn + wn * 64 +
                (lane & 3) * 16) = vvv;
    }
    if (t < 256)
      atomicAdd(&rowsum[(long)b * 4096 + bm + t], rs[t] + rs[256 + t]);
  } else {
    // epilogue: unnormalized PV partial -> bf16
    u16* D = Dg + (long)b * 4194304 + (long)ks * 2097152;
#pragma unroll
    for (int mi = 0; mi < 4; ++mi) {
      int m0 = bm + wm * 64 + mi * 16 + q * 4;
#pragma unroll
      for (int ni = 0; ni < 4; ++ni) {
        int n = bn + wn * 64 + ni * 16 + r16;
        f4v vv = acc[mi][ni];
#pragma unroll
        for (int r2 = 0; r2 < 4; ++r2)
          D[(long)(m0 + r2) * 512 + n] = f2bf(vv[r2]);
      }
    }
  }
  (void)rowsum;
}

// ---------------- bf16 NT GEMM (FINAL) ------------------------------------
template <int MODE, int BM, int BN>
__global__ __launch_bounds__(256) void gemm_nt(
    const u16* __restrict__ Ag, long sA, const u16* __restrict__ Btg, long sB,
    void* __restrict__ Cg, long sC, int nx, int nyg, int K, long lda, long ldb,
    int N, const float* __restrict__ b0, const float* __restrict__ resid,
    long sR, float scale) {
  constexpr int MI = BM / 32, NI = BN / 32;
  constexpr int AGW = BM / 64, BGW = BN / 64;
  constexpr int NLD = AGW + BGW;
  __shared__ __align__(16) u16 lds_a[3][BM * 32];
  __shared__ __align__(16) u16 lds_b[3][BN * 32];
  const int t = threadIdx.x;
  const int lane = t & 63, wv = t >> 6;
  const int wm = wv >> 1, wn = wv & 1;

  int lin = blockIdx.x;
  int xcd = lin & 7, s = lin >> 3;
  int bn_i = s % nx, t2 = s / nx;
  int bm_i = (t2 % nyg) * 8 + xcd;
  int bz = t2 / nyg;

  const u16* A = Ag + (long)bz * sA;
  const u16* Bt = Btg + (long)bz * sB;
  long c_off = (long)bz * sC;
  const int bm = bm_i * BM, bn = bn_i * BN;

  const u16* aP[AGW];
  const u16* bP[BGW];
#pragma unroll
  for (int j = 0; j < AGW; ++j)
    aP[j] = A + (long)(bm + (wv + j * 4) * 16 + (lane & 15)) * lda +
            (lane >> 4) * 8;
#pragma unroll
  for (int j = 0; j < BGW; ++j)
    bP[j] = Bt + (long)(bn + (wv + j * 4) * 16 + (lane & 15)) * ldb +
            (lane >> 4) * 8;

  auto issue = [&](int buf) {
#pragma unroll
    for (int j = 0; j < AGW; ++j) {
      gload16(aP[j], &lds_a[buf][(wv + j * 4) * 512 + lane * 8]);
      aP[j] += 32;
    }
#pragma unroll
    for (int j = 0; j < BGW; ++j) {
      gload16(bP[j], &lds_b[buf][(wv + j * 4) * 512 + lane * 8]);
      bP[j] += 32;
    }
  };

  f4v acc[MI][NI];
#pragma unroll
  for (int i = 0; i < MI; ++i)
#pragma unroll
    for (int j = 0; j < NI; ++j) acc[i][j] = (f4v){0.f, 0.f, 0.f, 0.f};

  const int NIT = K / 32;
  issue(0);
  issue(1);
  int cur = 0, nxt = 2;
  for (int it = 0; it < NIT; ++it) {
    if (it < NIT - 1)
      asm volatile("s_waitcnt vmcnt(%0)" ::"n"(NLD) : "memory");
    else
      asm volatile("s_waitcnt vmcnt(0)" ::: "memory");
    asm volatile("s_barrier" ::: "memory");
    if (it + 2 < NIT) issue(nxt);

    s8v af[MI], bfr[NI];
#pragma unroll
    for (int mi = 0; mi < MI; ++mi)
      af[mi] = *(const s8v*)&lds_a[cur][((wm * MI + mi) * 64 + lane) * 8];
#pragma unroll
    for (int ni = 0; ni < NI; ++ni)
      bfr[ni] = *(const s8v*)&lds_b[cur][((wn * NI + ni) * 64 + lane) * 8];
#pragma unroll
    for (int mi = 0; mi < MI; ++mi)
#pragma unroll
      for (int ni = 0; ni < NI; ++ni)
        acc[mi][ni] = __builtin_amdgcn_mfma_f32_16x16x32_bf16(
            af[mi], bfr[ni], acc[mi][ni], 0, 0, 0);
    cur = cur == 2 ? 0 : cur + 1;
    nxt = nxt == 2 ? 0 : nxt + 1;
  }

  const int quad = lane >> 4, col = lane & 15;
#pragma unroll
  for (int mi = 0; mi < MI; ++mi) {
#pragma unroll
    for (int ni = 0; ni < NI; ++ni) {
      int n = bn + wn * (BN / 2) + ni * 16 + col;
      int m0 = bm + wm * (BM / 2) + mi * 16 + quad * 4;
      f4v vv = acc[mi][ni];
#pragma unroll
      for (int r2 = 0; r2 < 4; ++r2) {
        int m = m0 + r2;
        float val = vv[r2];
        if constexpr (MODE == MODE_SCALE) val *= scale;
        if constexpr (MODE == MODE_FINAL) {
          val += b0[m] + resid[(long)bz * sR + (long)m * N + n];
          ((float*)Cg)[c_off + (long)m * N + n] = val;
        } else {
          ((u16*)Cg)[c_off + (long)m * N + n] = f2bf(val);
        }
      }
    }
  }
  (void)scale; (void)resid;
}

extern "C" void kernel_launch(void* const* d_in, const int* in_sizes, int n_in,
                              void* d_out, int out_size, void* d_ws,
                              size_t ws_size, hipStream_t stream) {
  const float* x = (const float*)d_in[0];
  const float* gamma = (const float*)d_in[1];
  const float* beta = (const float*)d_in[2];
  const float* wq = (const float*)d_in[3];
  const float* bq = (const float*)d_in[4];
  const float* wk = (const float*)d_in[5];
  const float* bk = (const float*)d_in[6];
  const float* wv = (const float*)d_in[7];
  const float* bv = (const float*)d_in[8];
  const float* wo = (const float*)d_in[9];
  const float* bo = (const float*)d_in[10];

  // ws_size = 256 MiB (observed: harness poison fill writes 262144 KB).
  u8* wsb = (u8*)d_ws;
  u16* hnt = (u16*)wsb;                  // 8M: hn^t bf16; later out_t
  u8* q8 = wsb + 8388608;                // 4M fp8 [2][4096][512] k-interleaved
  u8* k8 = wsb + 12582912;               // 4M
  u8* v8 = wsb + 16777216;               // 4M fp8 [2][512][4096] k-interleaved
  u16* wqb = (u16*)(wsb + 20971520);     // 2M: 4 weights bf16
  u16* wob = wqb + 786432;
  float2* part = (float2*)(wsb + 23068672);
  float* rowsum = (float*)(wsb + 25165824);  // 32K: [2][4096] f32
  u8* P8 = wsb + 92274688;               // 32M: [2][4096][4096] fp8 k-ilv
  u16* parts = (u16*)(wsb + 125829120);  // 16M: [2][2][4096][512] bf16

  // stats + weight cast + rowsum zero: one fat kernel
  prep<<<1540, 256, 0, stream>>>(x, wq, wk, wv, wo, part, wqb, rowsum);
  // groupnorm apply + transpose (AB recomputed per block from part)
  gn_apply_t<<<dim3(128, 16, 2), 256, 0, stream>>>(x, part, gamma, beta, hnt);

  // fused q/k/v (all fp8, k-interleaved): 512 blocks
  gemm_qkv3<<<512, 256, 0, stream>>>(hnt, wqb, q8, k8, v8, bq, bk, bv);

  // P8 = exp(scale * q8 k8^T - 1) + rowsum atomics: 1024 blocks (256x128)
  gemm8p<0><<<1024, 512, 0, stream>>>(q8, k8, (u16*)P8, rowsum);
  // PV fp8 split-K2 (unnormalized), both batches: 256 blocks (256x128)
  gemm8p<1><<<256, 512, 0, stream>>>(P8, v8, parts, rowsum);
  // out_t = (sum of 2 partials) / rowsum, both batches
  reduce_pv2<<<2048, 256, 0, stream>>>(parts, hnt, rowsum);

  // d_out = wo . out_t^T + bo + x: 64x128, nx=32, nyg=1, nz=2 -> 512 blocks
  gemm_nt<MODE_FINAL, 64, 128><<<512, 256, 0, stream>>>(
      wob, 0, hnt, 2097152, d_out, 2097152, 32, 1, 512, 512, 512, 4096, bo,
      x, 2097152, 0.f);

  (void)in_sizes; (void)n_in; (void)out_size; (void)ws_size;
}

// Round 10
// 191.803 us; speedup vs baseline: 1.1046x; 1.0687x over previous
//
#include <hip/hip_runtime.h>

typedef unsigned short u16;
typedef unsigned char u8;
typedef __attribute__((ext_vector_type(8))) short s8v;
typedef __attribute__((ext_vector_type(4))) float f4v;
typedef __attribute__((ext_vector_type(2))) long l2v;

enum { MODE_SCALE = 2, MODE_FINAL = 3 };

__device__ __forceinline__ u16 f2bf(float f) {
  unsigned u = __builtin_bit_cast(unsigned, f);
  u += 0x7fffu + ((u >> 16) & 1u);
  return (u16)(u >> 16);
}
__device__ __forceinline__ float bf2f(u16 h) {
  unsigned u = ((unsigned)h) << 16;
  return __builtin_bit_cast(float, u);
}
__device__ __forceinline__ void gload16(const void* g, void* l) {
  __builtin_amdgcn_global_load_lds(
      (const __attribute__((address_space(1))) unsigned int*)g,
      (__attribute__((address_space(3))) unsigned int*)l, 16, 0, 0);
}
__device__ __forceinline__ unsigned pk4fp8(float a, float b, float c, float d) {
  int lo = __builtin_amdgcn_cvt_pk_fp8_f32(a, b, 0, false);
  return (unsigned)__builtin_amdgcn_cvt_pk_fp8_f32(c, d, lo, true);
}
__device__ __forceinline__ u8 f2fp8(float a) {
  return (u8)(__builtin_amdgcn_cvt_pk_fp8_f32(a, a, 0, false) & 0xff);
}
// k-interleave permutation within each aligned 64B k-group: byte j ->
// ((j>>3)&3)*16 + ((j>>5)&1)*8 + (j&7).  Chunk q (16B) of a row then holds
// [k 8q..8q+7][k 32+8q..32+8q+7] = both MFMA k-slices for lane quad q.
// 4-aligned 4B blocks map to contiguous 4B (j&7 preserved).
__device__ __forceinline__ int kperm(int j) {
  return (j & ~63) | (((j >> 3) & 3) << 4) | (((j >> 5) & 1) << 3) | (j & 7);
}

// ------- prep fat kernel: gn partial stats + weight casts + zeroing -------
// blocks [0,512):    gn_stats (x partial sums, 2 channels/block)
// blocks [512,1536): wq/wk/wv -> fp8 k-ilv (w8); wo -> bf16 (wob)
// blocks [1536,1540): zero rowsum (2x4096 f32)
__global__ __launch_bounds__(256) void prep(
    const float* __restrict__ x, const float* __restrict__ w0,
    const float* __restrict__ w1, const float* __restrict__ w2,
    const float* __restrict__ w3, float2* __restrict__ part,
    u16* __restrict__ wob, u8* __restrict__ w8,
    float* __restrict__ rowsum) {
  const int bid = blockIdx.x;
  const int t = threadIdx.x;
  if (bid < 512) {
    const float4* p4 = (const float4*)(x + (long)bid * 8192);
    float s = 0.f, q = 0.f;
#pragma unroll
    for (int j = 0; j < 8; ++j) {
      float4 f = p4[t + 256 * j];
      s += f.x + f.y + f.z + f.w;
      q += f.x * f.x + f.y * f.y + f.z * f.z + f.w * f.w;
    }
#pragma unroll
    for (int o = 32; o; o >>= 1) {
      s += __shfl_xor(s, o, 64);
      q += __shfl_xor(q, o, 64);
    }
    __shared__ float rs[4], rq[4];
    int lane = t & 63, wv = t >> 6;
    if (lane == 0) { rs[wv] = s; rq[wv] = q; }
    __syncthreads();
    if (t == 0)
      part[bid] = make_float2(rs[0] + rs[1] + rs[2] + rs[3],
                              rq[0] + rq[1] + rq[2] + rq[3]);
  } else if (bid < 1536) {
    int wb = bid - 512;
    int which = wb >> 8;
    const float* w = which == 0 ? w0 : which == 1 ? w1 : which == 2 ? w2 : w3;
    int i = ((wb & 255) * 256 + t) * 4;
    float4 f = *(const float4*)(w + i);
    if (which == 3) {
      ushort4 r;
      r.x = f2bf(f.x); r.y = f2bf(f.y); r.z = f2bf(f.z); r.w = f2bf(f.w);
      *(ushort4*)(wob + i) = r;
    } else {
      // fp8 k-interleaved on the in-channel (col) axis
      *(unsigned*)(w8 + which * 262144 + (i & ~511) + kperm(i & 511)) =
          pk4fp8(f.x, f.y, f.z, f.w);
    }
  } else {
    int idx = (bid - 1536) * 256 + t;
    float4 z = {0.f, 0.f, 0.f, 0.f};
    *(float4*)(rowsum + idx * 8) = z;
    *(float4*)(rowsum + idx * 8 + 4) = z;
  }
}

// ------- apply groupnorm + transpose -> hn8 fp8 (k-interleaved chans) -----
__global__ __launch_bounds__(256) void gn_apply_t(const float* __restrict__ x,
                                                  const float2* __restrict__ part,
                                                  const float* __restrict__ gamma,
                                                  const float* __restrict__ beta,
                                                  u8* __restrict__ hn8) {
  int p0 = blockIdx.x * 32, c0 = blockIdx.y * 32, b = blockIdx.z;
  __shared__ float tile[32][33];
  __shared__ float2 ABs[32];
  int t = threadIdx.x;
  if (t < 32) {
    int c = c0 + t;
    int g = (b * 512 + c) >> 4;  // global 16-channel group
    float s = 0.f, q = 0.f;
#pragma unroll
    for (int j = 0; j < 8; ++j) {
      float2 pp = part[g * 8 + j];
      s += pp.x; q += pp.y;
    }
    float mean = s * (1.0f / 65536.0f);
    float var = q * (1.0f / 65536.0f) - mean * mean;
    float a = gamma[c] * rsqrtf(var + 1e-6f);
    ABs[t] = make_float2(a, beta[c] - mean * a);
  }
  const float* xb = x + (long)b * 2097152;
#pragma unroll
  for (int j = 0; j < 4; ++j) {
    int lc = (t >> 5) + j * 8, lp = t & 31;
    tile[lc][lp] = xb[(long)(c0 + lc) * 4096 + p0 + lp];
  }
  __syncthreads();
#pragma unroll
  for (int j = 0; j < 4; ++j) {
    int lp = (t >> 5) + j * 8, lc = t & 31;
    float2 ab = ABs[lc];
    float val = tile[lc][lp] * ab.x + ab.y;
    hn8[(long)b * 2097152 + (long)(p0 + lp) * 512 + kperm(c0 + lc)] =
        f2fp8(val);
  }
}

// ------- split-K4 reduce + rowsum normalize -> out_t (bf16) ---------------
__global__ __launch_bounds__(256) void reduce_pv4(const u16* __restrict__ parts,
                                                  u16* __restrict__ out,
                                                  const float* __restrict__ rowsum) {
  long i = ((long)blockIdx.x * 256 + threadIdx.x) * 8;  // [0, 4194304)
  long b = i >> 21, off = i & 2097151;
  const u16* base = parts + b * 8388608 + off;
  float inv = 1.0f / rowsum[b * 4096 + (off >> 9)];
  s8v a = *(const s8v*)(base);
  s8v bb = *(const s8v*)(base + 2097152);
  s8v c = *(const s8v*)(base + 4194304);
  s8v d = *(const s8v*)(base + 6291456);
  s8v o;
#pragma unroll
  for (int j = 0; j < 8; ++j)
    o[j] = (short)f2bf((bf2f((u16)a[j]) + bf2f((u16)bb[j]) + bf2f((u16)c[j]) +
                        bf2f((u16)d[j])) * inv);
  *(s8v*)(out + i) = o;
}

// ------- fused QKV GEMM, all-fp8 (hn8 . w8^T), clone of gemm8p K-loop -----
// A = hn8 [2][4096][512] fp8 k-ilv, B = w8 [1536][512] fp8 k-ilv (q,k,v
// stacked).  256x128 tile -> grid 16bm x 12bn x 2b = 384 blocks, 512 thr.
// Epilogue: w = bn>>9 (block-uniform): w<2 -> q8/k8[m][kperm(o)] bytes;
// w==2 -> v8[o][kperm(m)] pk4 dwords.  Bias added pre-quant.
__global__ __launch_bounds__(512, 4) void gemm_qkv8(
    const u8* __restrict__ hn8, const u8* __restrict__ w8,
    u8* __restrict__ q8, u8* __restrict__ k8, u8* __restrict__ v8,
    const float* __restrict__ bq, const float* __restrict__ bk,
    const float* __restrict__ bv) {
  constexpr int NKT = 8;
  constexpr long ld = 512;
  constexpr long ha = 128 * ld;
  constexpr int BUF = 24576;
  __shared__ __align__(16) u8 lds[73728];

  const int t = threadIdx.x;
  const int lane = t & 63, wv = t >> 6;
  const int wm = wv >> 1, wn = wv & 1;

  int lin = blockIdx.x;
  int xcd = lin & 7, s = lin >> 3;          // s in [0,48)
  int bn_i = s % 12, rest = s / 12;         // rest in [0,4)
  int bm_i = (rest & 1) * 8 + xcd;
  int b = rest >> 1;
  const int bm = bm_i * 256, bn = bn_i * 128;

  const u8* A = hn8 + (long)b * 2097152;
  const int tchunk = ((t & 3) ^ ((t >> 3) & 3)) * 16;
  const u8* pA0 = A + (long)(bm + (t >> 2)) * ld + tchunk;
  const u8* pB0 = w8 + (long)(bn + (t >> 2)) * ld + tchunk;

  const int r16 = lane & 15, q = lane >> 4;
  const int swz = (r16 >> 1) & 3;
  const int caq = (q ^ swz) * 16;
  const int aRow = (wm * 64 + r16) * 64;
  const int bRow = 16384 + (wn * 64 + r16) * 64;

  f4v acc[4][4];
#pragma unroll
  for (int i = 0; i < 4; ++i)
#pragma unroll
    for (int j = 0; j < 4; ++j) acc[i][j] = (f4v){0.f, 0.f, 0.f, 0.f};

#pragma unroll
  for (int T = 0; T < 2; ++T) {
    gload16(pA0 + T * 64, &lds[T * BUF + t * 16]);
    gload16(pA0 + ha + T * 64, &lds[T * BUF + 8192 + t * 16]);
    gload16(pB0 + T * 64, &lds[T * BUF + 16384 + t * 16]);
  }
  asm volatile("s_waitcnt vmcnt(3)" ::: "memory");
  asm volatile("s_barrier" ::: "memory");

  int cur = 0, nbuf = 2;
  const u8* pA = pA0 + 128;
  const u8* pB = pB0 + 128;
  for (int kt = 0; kt < NKT; ++kt) {
    const u8* LA = &lds[cur * BUF];
    u8* SB = &lds[nbuf * BUF];
    const bool st = kt <= NKT - 3;

    l2v af[4], bfv[4];
#pragma unroll
    for (int mi = 0; mi < 4; ++mi)
      af[mi] = *(const l2v*)(LA + aRow + mi * 1024 + caq);
#pragma unroll
    for (int ni = 0; ni < 4; ++ni)
      bfv[ni] = *(const l2v*)(LA + bRow + ni * 1024 + caq);

    if (st) gload16(pA, SB + t * 16);
    __builtin_amdgcn_s_setprio(1);
#pragma unroll
    for (int mi = 0; mi < 2; ++mi)
#pragma unroll
      for (int ni = 0; ni < 4; ++ni) {
        acc[mi][ni] = __builtin_amdgcn_mfma_f32_16x16x32_fp8_fp8(
            af[mi][0], bfv[ni][0], acc[mi][ni], 0, 0, 0);
        acc[mi][ni] = __builtin_amdgcn_mfma_f32_16x16x32_fp8_fp8(
            af[mi][1], bfv[ni][1], acc[mi][ni], 0, 0, 0);
      }
    __builtin_amdgcn_s_setprio(0);
    if (st) gload16(pA + ha, SB + 8192 + t * 16);
    __builtin_amdgcn_s_setprio(1);
#pragma unroll
    for (int mi = 2; mi < 4; ++mi)
#pragma unroll
      for (int ni = 0; ni < 4; ++ni) {
        acc[mi][ni] = __builtin_amdgcn_mfma_f32_16x16x32_fp8_fp8(
            af[mi][0], bfv[ni][0], acc[mi][ni], 0, 0, 0);
        acc[mi][ni] = __builtin_amdgcn_mfma_f32_16x16x32_fp8_fp8(
            af[mi][1], bfv[ni][1], acc[mi][ni], 0, 0, 0);
      }
    __builtin_amdgcn_s_setprio(0);
    if (st) gload16(pB, SB + 16384 + t * 16);

    if (kt < NKT - 1) {
      if (st)
        asm volatile("s_waitcnt vmcnt(3)" ::: "memory");
      else
        asm volatile("s_waitcnt vmcnt(0)" ::: "memory");
      asm volatile("s_barrier" ::: "memory");
    }
    pA += 64;
    pB += 64;
    cur = cur == 2 ? 0 : cur + 1;
    nbuf = nbuf == 2 ? 0 : nbuf + 1;
  }

  const int w = bn >> 9;  // block-uniform: 128-tile within one 512 window
  const float* bias = w == 0 ? bq : w == 1 ? bk : bv;
  u8* qkdst = (w == 0 ? q8 : k8) + (long)b * 2097152;
  u8* vdst = v8 + (long)b * 2097152;
#pragma unroll
  for (int mi = 0; mi < 4; ++mi) {
    int m0 = bm + wm * 64 + mi * 16 + q * 4;
#pragma unroll
    for (int ni = 0; ni < 4; ++ni) {
      int n = bn + wn * 64 + ni * 16 + r16;
      int o = n & 511;
      f4v vvv = acc[mi][ni];
      float bsv = bias[o];
      if (w == 2) {
        // v8[o][m]: pixel axis kperm'd (PV's K); m0%8 in {0,4}
        *(unsigned*)&vdst[(long)o * 4096 + kperm(m0)] =
            pk4fp8(vvv[0] + bsv, vvv[1] + bsv, vvv[2] + bsv, vvv[3] + bsv);
      } else {
        int op = kperm(o);
#pragma unroll
        for (int r2 = 0; r2 < 4; ++r2)
          qkdst[(long)(m0 + r2) * 512 + op] = f2fp8(vvv[r2] + bsv);
      }
    }
  }
}

// ---------------- fp8 256x128-tile GEMM, 1 barrier / K-tile ---------------
// GM==0: P8 = exp(scale*q8.k8^T - 1) fp8 k-ilv + rowsum atomics.
//        M=4096 N=4096 K=512.                        grid 1024, 512 thr
// GM==1: parts = P8 . v8^T (unnormalized, split-K4)  grid 512, 512 thr
// 256x128 tile, BK=64, 8 waves, 3 LDS buffers of 24KB (72KB -> 2 blocks/CU).
// Inputs k-interleaved (kperm): one ds_read_b128 per fragment pair; chunk
// swizzle (r16>>1)&3 keeps reads bank-conflict-free.  One s_barrier per
// K-tile; counted vmcnt(3) gate (3 staging loads/thread/tile).
// NOTE: body/signature must stay EXACTLY this r6-verified form — r5's
// finisher graft flipped regalloc to VGPR=64 (acc spilled, 5.3x); r8's
// (512,2) reg-pipeline dropped to 1 block/CU; r9's split-K2 lost 2-blk/CU
// overlap.  Keep (512,4), split-K4, grids 1024/512.
template <int GM>
__global__ __launch_bounds__(512, 4) void gemm8p(const u8* __restrict__ Ag,
                                                 const u8* __restrict__ Bg,
                                                 u16* __restrict__ Dg,
                                                 float* __restrict__ rowsum) {
  constexpr int NKT = GM == 0 ? 8 : 16;
  constexpr long ld = GM == 0 ? 512 : 4096;  // A and B K-stride (bytes)
  constexpr int nx = GM == 0 ? 32 : 4;       // N tiles (128-wide)
  constexpr long ha = 128 * ld;              // A half-tile (128 rows)
  constexpr int BUF = 24576;
  __shared__ __align__(16) u8 lds[73728];

  const int t = threadIdx.x;
  const int lane = t & 63, wv = t >> 6;
  const int wm = wv >> 1, wn = wv & 1;

  int lin = blockIdx.x;
  int xcd = lin & 7, s = lin >> 3;
  int bn_i = s % nx, rest = s / nx;
  int bm_i = (rest & 1) * 8 + xcd, rest2 = rest >> 1;
  int ks = 0, b;
  if constexpr (GM == 1) {
    ks = rest2 & 3;
    b = rest2 >> 2;
  } else {
    b = rest2;
  }
  const int bm = bm_i * 256, bn = bn_i * 128;

  const u8* A = Ag + (long)b * (GM == 0 ? 2097152 : 16777216);
  const u8* B = Bg + (long)b * 2097152;
  const long k0 = GM == 1 ? (long)ks * 1024 : 0;

  // staging: thread t covers row (t>>2), 16B chunk (t&3); source chunk
  // pre-swizzled so LDS holds row[chunk ^ ((row>>1)&3)].
  const int tchunk = ((t & 3) ^ ((t >> 3) & 3)) * 16;
  const u8* pA0 = A + (long)(bm + (t >> 2)) * ld + k0 + tchunk;
  const u8* pB0 = B + (long)(bn + (t >> 2)) * ld + k0 + tchunk;

  // per-lane read constants: fragment row = lane&15, chunk = lane>>4
  const int r16 = lane & 15, q = lane >> 4;
  const int swz = (r16 >> 1) & 3;
  const int caq = (q ^ swz) * 16;
  const int aRow = (wm * 64 + r16) * 64;           // A zone [0,16384)
  const int bRow = 16384 + (wn * 64 + r16) * 64;   // B zone [16384,24576)

  f4v acc[4][4];
#pragma unroll
  for (int i = 0; i < 4; ++i)
#pragma unroll
    for (int j = 0; j < 4; ++j) acc[i][j] = (f4v){0.f, 0.f, 0.f, 0.f};

  // prologue: stage K-tiles 0,1 into bufs 0,1 (6 loads/thread)
#pragma unroll
  for (int T = 0; T < 2; ++T) {
    gload16(pA0 + T * 64, &lds[T * BUF + t * 16]);
    gload16(pA0 + ha + T * 64, &lds[T * BUF + 8192 + t * 16]);
    gload16(pB0 + T * 64, &lds[T * BUF + 16384 + t * 16]);
  }
  asm volatile("s_waitcnt vmcnt(3)" ::: "memory");  // tile 0 landed
  asm volatile("s_barrier" ::: "memory");

  int cur = 0, nbuf = 2;
  const u8* pA = pA0 + 128;  // tile kt+2 source
  const u8* pB = pB0 + 128;
  for (int kt = 0; kt < NKT; ++kt) {
    const u8* LA = &lds[cur * BUF];
    u8* SB = &lds[nbuf * BUF];
    const bool st = kt <= NKT - 3;

    l2v af[4], bfv[4];
#pragma unroll
    for (int mi = 0; mi < 4; ++mi)
      af[mi] = *(const l2v*)(LA + aRow + mi * 1024 + caq);
#pragma unroll
    for (int ni = 0; ni < 4; ++ni)
      bfv[ni] = *(const l2v*)(LA + bRow + ni * 1024 + caq);

    if (st) gload16(pA, SB + t * 16);
    __builtin_amdgcn_s_setprio(1);
#pragma unroll
    for (int mi = 0; mi < 2; ++mi)
#pragma unroll
      for (int ni = 0; ni < 4; ++ni) {
        acc[mi][ni] = __builtin_amdgcn_mfma_f32_16x16x32_fp8_fp8(
            af[mi][0], bfv[ni][0], acc[mi][ni], 0, 0, 0);
        acc[mi][ni] = __builtin_amdgcn_mfma_f32_16x16x32_fp8_fp8(
            af[mi][1], bfv[ni][1], acc[mi][ni], 0, 0, 0);
      }
    __builtin_amdgcn_s_setprio(0);
    if (st) gload16(pA + ha, SB + 8192 + t * 16);
    __builtin_amdgcn_s_setprio(1);
#pragma unroll
    for (int mi = 2; mi < 4; ++mi)
#pragma unroll
      for (int ni = 0; ni < 4; ++ni) {
        acc[mi][ni] = __builtin_amdgcn_mfma_f32_16x16x32_fp8_fp8(
            af[mi][0], bfv[ni][0], acc[mi][ni], 0, 0, 0);
        acc[mi][ni] = __builtin_amdgcn_mfma_f32_16x16x32_fp8_fp8(
            af[mi][1], bfv[ni][1], acc[mi][ni], 0, 0, 0);
      }
    __builtin_amdgcn_s_setprio(0);
    if (st) gload16(pB, SB + 16384 + t * 16);

    if (kt < NKT - 1) {
      if (st)
        asm volatile("s_waitcnt vmcnt(3)" ::: "memory");
      else
        asm volatile("s_waitcnt vmcnt(0)" ::: "memory");
      asm volatile("s_barrier" ::: "memory");
    }
    pA += 64;
    pB += 64;
    cur = cur == 2 ? 0 : cur + 1;
    nbuf = nbuf == 2 ? 0 : nbuf + 1;
  }

  if constexpr (GM == 0) {
    // epilogue: E = exp(S*scale - 1) -> LDS pack -> coalesced fp8 stores,
    // plus per-row sums -> LDS -> one atomicAdd per row per block.
    const float qk = 0.044194173824159216f;
    u8* Pb = (u8*)Dg + (long)b * 16777216;
    __syncthreads();  // all K-loop LDS reads done; reuse lds
    u8* zone = lds + wv * 4096;            // [64 rows][64B], q-xor swizzled
    float* rs = (float*)(lds + 32768);     // [2][256] f32
#pragma unroll
    for (int mi = 0; mi < 4; ++mi) {
      f4v sum4 = (f4v){0.f, 0.f, 0.f, 0.f};
#pragma unroll
      for (int ni = 0; ni < 4; ++ni) {
        int np = kperm(ni * 16 + r16);
        f4v vv = acc[mi][ni];
#pragma unroll
        for (int r2 = 0; r2 < 4; ++r2) {
          float e = __expf(vv[r2] * qk - 1.0f);
          zone[(mi * 16 + q * 4 + r2) * 64 + (np ^ (q << 4))] = f2fp8(e);
          sum4[r2] += e;
        }
      }
#pragma unroll
      for (int o = 8; o; o >>= 1) {
        sum4[0] += __shfl_xor(sum4[0], o, 64);
        sum4[1] += __shfl_xor(sum4[1], o, 64);
        sum4[2] += __shfl_xor(sum4[2], o, 64);
        sum4[3] += __shfl_xor(sum4[3], o, 64);
      }
      if (r16 == 0)
        *(float4*)&rs[wn * 256 + wm * 64 + mi * 16 + q * 4] =
            make_float4(sum4[0], sum4[1], sum4[2], sum4[3]);
    }
    __syncthreads();
#pragma unroll
    for (int i = 0; i < 4; ++i) {
      int zr = i * 16 + (lane >> 2);
      int pc = (lane & 3) ^ ((lane >> 4) & 3);
      uint4 vvv = *(const uint4*)(zone + zr * 64 + pc * 16);
      *(uint4*)(Pb + (long)(bm + wm * 64 + zr) * 4096 + bn + wn * 64 +
                (lane & 3) * 16) = vvv;
    }
    if (t < 256)
      atomicAdd(&rowsum[(long)b * 4096 + bm + t], rs[t] + rs[256 + t]);
  } else {
    // epilogue: unnormalized PV partial -> bf16
    u16* D = Dg + (long)b * 8388608 + (long)ks * 2097152;
#pragma unroll
    for (int mi = 0; mi < 4; ++mi) {
      int m0 = bm + wm * 64 + mi * 16 + q * 4;
#pragma unroll
      for (int ni = 0; ni < 4; ++ni) {
        int n = bn + wn * 64 + ni * 16 + r16;
        f4v vv = acc[mi][ni];
#pragma unroll
        for (int r2 = 0; r2 < 4; ++r2)
          D[(long)(m0 + r2) * 512 + n] = f2bf(vv[r2]);
      }
    }
  }
  (void)rowsum;
}

// ---------------- bf16 NT GEMM (FINAL) ------------------------------------
template <int MODE, int BM, int BN>
__global__ __launch_bounds__(256) void gemm_nt(
    const u16* __restrict__ Ag, long sA, const u16* __restrict__ Btg, long sB,
    void* __restrict__ Cg, long sC, int nx, int nyg, int K, long lda, long ldb,
    int N, const float* __restrict__ b0, const float* __restrict__ resid,
    long sR, float scale) {
  constexpr int MI = BM / 32, NI = BN / 32;
  constexpr int AGW = BM / 64, BGW = BN / 64;
  constexpr int NLD = AGW + BGW;
  __shared__ __align__(16) u16 lds_a[3][BM * 32];
  __shared__ __align__(16) u16 lds_b[3][BN * 32];
  const int t = threadIdx.x;
  const int lane = t & 63, wv = t >> 6;
  const int wm = wv >> 1, wn = wv & 1;

  int lin = blockIdx.x;
  int xcd = lin & 7, s = lin >> 3;
  int bn_i = s % nx, t2 = s / nx;
  int bm_i = (t2 % nyg) * 8 + xcd;
  int bz = t2 / nyg;

  const u16* A = Ag + (long)bz * sA;
  const u16* Bt = Btg + (long)bz * sB;
  long c_off = (long)bz * sC;
  const int bm = bm_i * BM, bn = bn_i * BN;

  const u16* aP[AGW];
  const u16* bP[BGW];
#pragma unroll
  for (int j = 0; j < AGW; ++j)
    aP[j] = A + (long)(bm + (wv + j * 4) * 16 + (lane & 15)) * lda +
            (lane >> 4) * 8;
#pragma unroll
  for (int j = 0; j < BGW; ++j)
    bP[j] = Bt + (long)(bn + (wv + j * 4) * 16 + (lane & 15)) * ldb +
            (lane >> 4) * 8;

  auto issue = [&](int buf) {
#pragma unroll
    for (int j = 0; j < AGW; ++j) {
      gload16(aP[j], &lds_a[buf][(wv + j * 4) * 512 + lane * 8]);
      aP[j] += 32;
    }
#pragma unroll
    for (int j = 0; j < BGW; ++j) {
      gload16(bP[j], &lds_b[buf][(wv + j * 4) * 512 + lane * 8]);
      bP[j] += 32;
    }
  };

  f4v acc[MI][NI];
#pragma unroll
  for (int i = 0; i < MI; ++i)
#pragma unroll
    for (int j = 0; j < NI; ++j) acc[i][j] = (f4v){0.f, 0.f, 0.f, 0.f};

  const int NIT = K / 32;
  issue(0);
  issue(1);
  int cur = 0, nxt = 2;
  for (int it = 0; it < NIT; ++it) {
    if (it < NIT - 1)
      asm volatile("s_waitcnt vmcnt(%0)" ::"n"(NLD) : "memory");
    else
      asm volatile("s_waitcnt vmcnt(0)" ::: "memory");
    asm volatile("s_barrier" ::: "memory");
    if (it + 2 < NIT) issue(nxt);

    s8v af[MI], bfr[NI];
#pragma unroll
    for (int mi = 0; mi < MI; ++mi)
      af[mi] = *(const s8v*)&lds_a[cur][((wm * MI + mi) * 64 + lane) * 8];
#pragma unroll
    for (int ni = 0; ni < NI; ++ni)
      bfr[ni] = *(const s8v*)&lds_b[cur][((wn * NI + ni) * 64 + lane) * 8];
#pragma unroll
    for (int mi = 0; mi < MI; ++mi)
#pragma unroll
      for (int ni = 0; ni < NI; ++ni)
        acc[mi][ni] = __builtin_amdgcn_mfma_f32_16x16x32_bf16(
            af[mi], bfr[ni], acc[mi][ni], 0, 0, 0);
    cur = cur == 2 ? 0 : cur + 1;
    nxt = nxt == 2 ? 0 : nxt + 1;
  }

  const int quad = lane >> 4, col = lane & 15;
#pragma unroll
  for (int mi = 0; mi < MI; ++mi) {
#pragma unroll
    for (int ni = 0; ni < NI; ++ni) {
      int n = bn + wn * (BN / 2) + ni * 16 + col;
      int m0 = bm + wm * (BM / 2) + mi * 16 + quad * 4;
      f4v vv = acc[mi][ni];
#pragma unroll
      for (int r2 = 0; r2 < 4; ++r2) {
        int m = m0 + r2;
        float val = vv[r2];
        if constexpr (MODE == MODE_SCALE) val *= scale;
        if constexpr (MODE == MODE_FINAL) {
          val += b0[m] + resid[(long)bz * sR + (long)m * N + n];
          ((float*)Cg)[c_off + (long)m * N + n] = val;
        } else {
          ((u16*)Cg)[c_off + (long)m * N + n] = f2bf(val);
        }
      }
    }
  }
  (void)scale; (void)resid;
}

extern "C" void kernel_launch(void* const* d_in, const int* in_sizes, int n_in,
                              void* d_out, int out_size, void* d_ws,
                              size_t ws_size, hipStream_t stream) {
  const float* x = (const float*)d_in[0];
  const float* gamma = (const float*)d_in[1];
  const float* beta = (const float*)d_in[2];
  const float* wq = (const float*)d_in[3];
  const float* bq = (const float*)d_in[4];
  const float* wk = (const float*)d_in[5];
  const float* bk = (const float*)d_in[6];
  const float* wv = (const float*)d_in[7];
  const float* bv = (const float*)d_in[8];
  const float* wo = (const float*)d_in[9];
  const float* bo = (const float*)d_in[10];

  // ws_size = 256 MiB (observed: harness poison fill writes 262144 KB).
  u8* wsb = (u8*)d_ws;
  u16* hnt = (u16*)wsb;                  // 8M: out_t bf16 (reduce output)
  u8* q8 = wsb + 8388608;                // 4M fp8 [2][4096][512] k-interleaved
  u8* k8 = wsb + 12582912;               // 4M
  u8* v8 = wsb + 16777216;               // 4M fp8 [2][512][4096] k-interleaved
  u16* wob = (u16*)(wsb + 20971520);     // 512K: wo bf16
  u8* w8 = wsb + 21495808;               // 768K: wq/wk/wv fp8 k-ilv [1536][512]
  float2* part = (float2*)(wsb + 23068672);
  float* rowsum = (float*)(wsb + 25165824);  // 32K: [2][4096] f32
  u8* hn8 = wsb + 27262976;              // 4M fp8 [2][4096][512] k-ilv chans
  u8* P8 = wsb + 92274688;               // 32M: [2][4096][4096] fp8 k-ilv
  u16* parts = (u16*)(wsb + 125829120);  // 32M: [2][4][4096][512] bf16

  // stats + weight casts + rowsum zero: one fat kernel
  prep<<<1540, 256, 0, stream>>>(x, wq, wk, wv, wo, part, wob, w8, rowsum);
  // groupnorm apply + transpose -> hn8 fp8
  gn_apply_t<<<dim3(128, 16, 2), 256, 0, stream>>>(x, part, gamma, beta, hn8);

  // fused q/k/v, all-fp8 GEMM: 384 blocks (256x128 over stacked weights)
  gemm_qkv8<<<384, 512, 0, stream>>>(hn8, w8, q8, k8, v8, bq, bk, bv);

  // P8 = exp(scale * q8 k8^T - 1) + rowsum atomics: 1024 blocks (256x128)
  gemm8p<0><<<1024, 512, 0, stream>>>(q8, k8, (u16*)P8, rowsum);
  // PV fp8 split-K4 (unnormalized), both batches: 512 blocks (256x128)
  gemm8p<1><<<512, 512, 0, stream>>>(P8, v8, parts, rowsum);
  // out_t = (sum of 4 partials) / rowsum, both batches
  reduce_pv4<<<2048, 256, 0, stream>>>(parts, hnt, rowsum);

  // d_out = wo . out_t^T + bo + x: 64x128, nx=32, nyg=1, nz=2 -> 512 blocks
  gemm_nt<MODE_FINAL, 64, 128><<<512, 256, 0, stream>>>(
      wob, 0, hnt, 2097152, d_out, 2097152, 32, 1, 512, 512, 512, 4096, bo,
      x, 2097152, 0.f);

  (void)in_sizes; (void)n_in; (void)out_size; (void)ws_size;
}